// Round 13
// baseline (174.306 us; speedup 1.0000x reference)
//
#include <hip/hip_runtime.h>
#include <hip/hip_bf16.h>
#include <math.h>

#define B 4096
#define NF 50
#define BN_EPS 1e-3f
#define ROWS 16

typedef float f32x4 __attribute__((ext_vector_type(4)));
typedef __bf16 bf16x8 __attribute__((ext_vector_type(8)));
#define MFMA __builtin_amdgcn_mfma_f32_16x16x32_bf16

__device__ __forceinline__ unsigned short f2b(float x) {
  unsigned u = __float_as_uint(x);
  return (unsigned short)((u + 0x7FFFu + ((u >> 16) & 1u)) >> 16);  // RNE
}
__device__ __forceinline__ unsigned packbf(float a, float b) {
  return ((unsigned)f2b(b) << 16) | (unsigned)f2b(a);
}
__device__ __forceinline__ float bs2f(unsigned short u) {
  return __uint_as_float(((unsigned)u) << 16);
}

// ---- workspace (unsigned short elems), all B-operands n-major/k-contig ----
#define WS_LS  0        // [64][3200]
#define WS_QW  204800   // [64][4096]
#define WS_W0  466944   // [512][192]
#define WS_W1  565248   // [256][512]
#define WS_W2  696320   // [128][256]

// ===========================================================================
// prep (proven): bf16 convert + W transposes via LDS tiles
__global__ __launch_bounds__(256) void prep(
    const float* __restrict__ ls, const float* __restrict__ qw,
    const float* __restrict__ W0, const float* __restrict__ W1,
    const float* __restrict__ W2, unsigned short* __restrict__ ws)
{
  int bid = blockIdx.x, t = threadIdx.x;
  if (bid < 228) {                // ls (100 blocks) + qw (128 blocks)
    int o = (bid * 256 + t) * 8;
    const float* src = (o < 204800) ? (ls + o) : (qw + (o - 204800));
    float4 a = *(const float4*)src, b = *(const float4*)(src + 4);
    int4 v = {(int)packbf(a.x, a.y), (int)packbf(a.z, a.w),
              (int)packbf(b.x, b.y), (int)packbf(b.z, b.w)};
    *(int4*)&ws[o] = v;
    return;
  }
  __shared__ unsigned short sh[64 * 72];
  int id = bid - 228;
  const float* W; int K, Ncols, kt, nt, wofs;
  if (id < 24)      { W = W0; K = 192; Ncols = 512; kt = id >> 3; nt = id & 7;  wofs = WS_W0; }
  else if (id < 56) { int j = id - 24; W = W1; K = 512; Ncols = 256; kt = j >> 2; nt = j & 3; wofs = WS_W1; }
  else              { int j = id - 56; W = W2; K = 256; Ncols = 128; kt = j >> 1; nt = j & 1; wofs = WS_W2; }
  int k0 = kt * 64, n0 = nt * 64;
  {
    int r = t >> 2, cs = (t & 3) * 16;
    const float* src = W + (size_t)(k0 + r) * Ncols + n0 + cs;
    float4 a = *(const float4*)src, b = *(const float4*)(src + 4);
    float4 c = *(const float4*)(src + 8), d = *(const float4*)(src + 12);
    unsigned short* dst = &sh[r * 72 + cs];
    *(int4*)dst = int4{(int)packbf(a.x, a.y), (int)packbf(a.z, a.w),
                       (int)packbf(b.x, b.y), (int)packbf(b.z, b.w)};
    *(int4*)(dst + 8) = int4{(int)packbf(c.x, c.y), (int)packbf(c.z, c.w),
                             (int)packbf(d.x, d.y), (int)packbf(d.z, d.w)};
  }
  __syncthreads();
  {
    int nr = t >> 2, ks = (t & 3) * 16;
    unsigned short vbuf[16];
#pragma unroll
    for (int j = 0; j < 16; ++j) vbuf[j] = sh[(ks + j) * 72 + nr];
    unsigned short* dst = &ws[wofs + (size_t)(n0 + nr) * K + k0 + ks];
    *(int4*)dst = *(int4*)&vbuf[0];
    *(int4*)(dst + 8) = *(int4*)&vbuf[8];
  }
}

// ===========================================================================
// 256 blocks x 1024 threads (16 waves), 16 rows/block, 7 barriers.
// Gather: wave = row, half-wave = field parity, s combined via shfl_xor(32).
// GEMMs: wave = (d-tile x K-half), partials via redA/redB (r5-proven pattern).
// All LDS: single-writer -> barrier -> read. Batched loads throughout (r12).
__global__ __launch_bounds__(1024, 4) void pnn_main(
    const float* __restrict__ fv, const int* __restrict__ idx,
    const float* __restrict__ emb, const float* __restrict__ theta,
    const unsigned short* __restrict__ ws,
    const float* __restrict__ b0p, const float* __restrict__ g0p,
    const float* __restrict__ be0p, const float* __restrict__ m0p,
    const float* __restrict__ v0p,
    const float* __restrict__ b1p, const float* __restrict__ g1p,
    const float* __restrict__ be1p, const float* __restrict__ m1p,
    const float* __restrict__ v1p,
    const float* __restrict__ b2p, const float* __restrict__ g2p,
    const float* __restrict__ be2p, const float* __restrict__ m2p,
    const float* __restrict__ v2p,
    const float* __restrict__ Wout, const float* __restrict__ boutp,
    float* __restrict__ out)
{
  __shared__ unsigned short feats[25 * 16 * 136];  // 108.8 KB; aliased later
  __shared__ int   idx_s[ROWS * NF];
  __shared__ float fv_s[ROWS * NF];
  __shared__ float th2t_s[NF * 64];                // transposed: [n][d]
  __shared__ float s_s[ROWS * 68];
  __shared__ float sq_s[ROWS * 64];
  __shared__ float redA[2 * ROWS * 66];            // l_z K-half partials
  __shared__ float redB[2 * ROWS * 66];            // l_p_out K-half partials
  __shared__ unsigned short x_s[ROWS * 200];       // [16][192+8]

  unsigned short* h0_s = feats;                    // [16][520]
  unsigned short* h1_s = feats + 8320;             // [16][264]
  unsigned short* h2_s = feats + 12544;            // [16][136]

  const unsigned short* lsb = ws + WS_LS;
  const unsigned short* qwb = ws + WS_QW;
  const unsigned short* w0t = ws + WS_W0;
  const unsigned short* w1t = ws + WS_W1;
  const unsigned short* w2t = ws + WS_W2;

  const int t    = threadIdx.x;
  const int w    = t >> 6;          // wave 0..15
  const int l    = t & 63;
  const int m16  = l & 15;
  const int qoff = (l >> 4) * 8;
  const int b0   = blockIdx.x * ROWS;

  // ---------------- phase 0: idx/fv/theta^2 (transposed) ----------------
  for (int i = t; i < ROWS * NF; i += 1024) {
    idx_s[i] = idx[b0 * NF + i];
    fv_s[i]  = fv[b0 * NF + i];
  }
  for (int i = t; i < NF * 64; i += 1024) {
    int n = i >> 6, d = i & 63;
    float v = theta[d * NF + n];
    th2t_s[i] = v * v;
  }
  __syncthreads();   // barrier 1

  // ---------------- phase 1: gather (wave=row, half-wave=parity) ----------
  {
    const int row = w;
    const int p   = l >> 5;          // field parity
    const int m2  = (l & 31) * 2;
    const int base = row * NF;
    float s0 = 0.f, s1 = 0.f;
    // fields n = 2j+p, j=0..24; two load groups {13,12}
    {
      float2 e[13];
#pragma unroll
      for (int j = 0; j < 13; ++j) {
        int iv = idx_s[base + 2 * j + p];
        e[j] = *(const float2*)(emb + (size_t)iv * 64 + m2);
      }
#pragma unroll
      for (int j = 0; j < 13; ++j) {
        int n = 2 * j + p;
        float fvv = fv_s[base + n];
        float p0 = fvv * e[j].x, p1 = fvv * e[j].y;
        *(unsigned*)&feats[j * 2176 + row * 136 + p * 64 + m2] = packbf(p0, p1);
        s0 += p0; s1 += p1;
        float q = p0 * p0 + p1 * p1;
        q += __shfl_xor(q, 16); q += __shfl_xor(q, 8); q += __shfl_xor(q, 4);
        q += __shfl_xor(q, 2);  q += __shfl_xor(q, 1);
        if ((l & 31) == 0) sq_s[row * 64 + n] = q;
      }
    }
    {
      float2 e[12];
#pragma unroll
      for (int j = 13; j < 25; ++j) {
        int iv = idx_s[base + 2 * j + p];
        e[j - 13] = *(const float2*)(emb + (size_t)iv * 64 + m2);
      }
#pragma unroll
      for (int j = 13; j < 25; ++j) {
        int n = 2 * j + p;
        float fvv = fv_s[base + n];
        float p0 = fvv * e[j - 13].x, p1 = fvv * e[j - 13].y;
        *(unsigned*)&feats[j * 2176 + row * 136 + p * 64 + m2] = packbf(p0, p1);
        s0 += p0; s1 += p1;
        float q = p0 * p0 + p1 * p1;
        q += __shfl_xor(q, 16); q += __shfl_xor(q, 8); q += __shfl_xor(q, 4);
        q += __shfl_xor(q, 2);  q += __shfl_xor(q, 1);
        if ((l & 31) == 0) sq_s[row * 64 + n] = q;
      }
    }
    // combine parity halves of s within the wave (lane ^ 32 has same m2)
    s0 += __shfl_xor(s0, 32);
    s1 += __shfl_xor(s1, 32);
    if (l < 32) {
      float2 sv; sv.x = s0; sv.y = s1;
      *(float2*)&s_s[row * 68 + m2] = sv;
    }
  }
  __syncthreads();   // barrier 2

  // ---------------- phase 2: per-wave GEMMs, d-tile x K-half --------------
  if (w < 8) {
    // l_z: dt = w>>1, kh = w&1; chunks [0,13) / [13,25)
    const int dt = w >> 1, kh = w & 1;
    const int c0 = kh ? 13 : 0, c1 = kh ? 25 : 13;
    f32x4 a0v = {0.f, 0.f, 0.f, 0.f}, a1v = {0.f, 0.f, 0.f, 0.f};
    const unsigned short* lp0 = lsb + (size_t)(dt * 16 + m16) * 3200 + qoff;
    const int arow = m16 * 136 + qoff;
    for (int cg = c0; cg < c1; cg += 4) {
      bf16x8 bv[16];
#pragma unroll
      for (int u = 0; u < 4; ++u) {
        int cc = cg + u;
        if (cc < c1) {
          const unsigned short* lp = lp0 + cc * 128;
#pragma unroll
          for (int s4 = 0; s4 < 4; ++s4)
            bv[u * 4 + s4] = *(const bf16x8*)(lp + s4 * 32);
        }
      }
#pragma unroll
      for (int u = 0; u < 4; ++u) {
        int cc = cg + u;
        if (cc < c1) {
          const unsigned short* fc = feats + cc * 2176 + arow;
#pragma unroll
          for (int s4 = 0; s4 < 4; ++s4) {
            bf16x8 av = *(const bf16x8*)(fc + s4 * 32);
            if (s4 & 1) a1v = MFMA(av, bv[u * 4 + s4], a1v, 0, 0, 0);
            else        a0v = MFMA(av, bv[u * 4 + s4], a0v, 0, 0, 0);
          }
        }
      }
    }
#pragma unroll
    for (int r = 0; r < 4; ++r)
      redA[kh * 1056 + ((l >> 4) * 4 + r) * 66 + dt * 16 + m16] = a0v[r] + a1v[r];
  } else {
    // l_p_out: dt = (w-8)>>1, kh = w&1; m in [32kh, 32kh+32), P in-register
    const int dt = (w - 8) >> 1, kh = w & 1;
    const int row = m16;
    const int nb = qoff;
    float sn[16];
    *(float4*)&sn[0]  = *(const float4*)&s_s[row * 68 + nb];
    *(float4*)&sn[4]  = *(const float4*)&s_s[row * 68 + nb + 4];
    *(float4*)&sn[8]  = *(const float4*)&s_s[row * 68 + 32 + nb];
    *(float4*)&sn[12] = *(const float4*)&s_s[row * 68 + 32 + nb + 4];
    f32x4 a0v = {0.f, 0.f, 0.f, 0.f}, a1v = {0.f, 0.f, 0.f, 0.f};
    const unsigned short* qp0 = qwb + (size_t)(dt * 16 + m16) * 4096 + qoff;
    for (int g = 0; g < 4; ++g) {
      bf16x8 bv[16];
#pragma unroll
      for (int mi = 0; mi < 8; ++mi) {
        int mm = kh * 32 + g * 8 + mi;
        const unsigned short* qp = qp0 + mm * 64;
        bv[2 * mi]     = *(const bf16x8*)qp;
        bv[2 * mi + 1] = *(const bf16x8*)(qp + 32);
      }
#pragma unroll
      for (int mi = 0; mi < 8; ++mi) {
        float sm = s_s[row * 68 + kh * 32 + g * 8 + mi];
        union { unsigned u[4]; bf16x8 v; } af0, af1;
#pragma unroll
        for (int j = 0; j < 4; ++j) {
          af0.u[j] = packbf(sm * sn[2 * j],     sm * sn[2 * j + 1]);
          af1.u[j] = packbf(sm * sn[8 + 2 * j], sm * sn[8 + 2 * j + 1]);
        }
        a0v = MFMA(af0.v, bv[2 * mi],     a0v, 0, 0, 0);
        a1v = MFMA(af1.v, bv[2 * mi + 1], a1v, 0, 0, 0);
      }
    }
#pragma unroll
    for (int r = 0; r < 4; ++r)
      redB[kh * 1056 + ((l >> 4) * 4 + r) * 66 + dt * 16 + m16] = a0v[r] + a1v[r];
  }
  __syncthreads();   // barrier 3

  // ---------------- phase 2.5: combine x + l_p_in (wave = row) ------------
  {
    float lz = redA[w * 66 + l] + redA[1056 + w * 66 + l];
    x_s[w * 200 + l] = f2b(lz);
    float lp = redB[w * 66 + l] + redB[1056 + w * 66 + l];
    x_s[w * 200 + 128 + l] = f2b(lp);
    float a = 0.f;
    for (int n = 0; n < NF; ++n)
      a += sq_s[w * 64 + n] * th2t_s[n * 64 + l];
    x_s[w * 200 + 64 + l] = f2b(a);
  }
  __syncthreads();   // barrier 4 (feats dead; h-buffers alias it)

  // ---------------- phase 3: MLP (batched W-frags, 16 waves) --------------
  // layer 0: 192 -> 512, 2 n-tiles per wave
  {
    int ar = m16 * 200 + qoff;
    bf16x8 xa[6];
#pragma unroll
    for (int kc = 0; kc < 6; ++kc) xa[kc] = *(const bf16x8*)&x_s[ar + kc * 32];
    for (int j = 0; j < 2; ++j) {
      int n0 = (w * 2 + j) * 16;
      const unsigned short* wp = w0t + (size_t)(n0 + m16) * 192 + qoff;
      bf16x8 bv[6];
#pragma unroll
      for (int kc = 0; kc < 6; ++kc) bv[kc] = *(const bf16x8*)(wp + kc * 32);
      f32x4 ha = {0.f, 0.f, 0.f, 0.f}, hb = {0.f, 0.f, 0.f, 0.f};
#pragma unroll
      for (int kc = 0; kc < 6; ++kc) {
        if (kc & 1) hb = MFMA(xa[kc], bv[kc], hb, 0, 0, 0);
        else        ha = MFMA(xa[kc], bv[kc], ha, 0, 0, 0);
      }
      int n = n0 + m16;
      float sc = g0p[n] * rsqrtf(v0p[n] + BN_EPS);
      float sh = be0p[n] + (b0p[n] - m0p[n]) * sc;
#pragma unroll
      for (int r = 0; r < 4; ++r) {
        float v = fmaxf((ha[r] + hb[r]) * sc + sh, 0.f);
        h0_s[((l >> 4) * 4 + r) * 520 + n] = f2b(v);
      }
    }
  }
  __syncthreads();   // barrier 5

  // layer 1: 512 -> 256, 1 n-tile per wave
  {
    int n0 = w * 16;
    const unsigned short* wp = w1t + (size_t)(n0 + m16) * 512 + qoff;
    bf16x8 bv[16];
#pragma unroll
    for (int kc = 0; kc < 16; ++kc) bv[kc] = *(const bf16x8*)(wp + kc * 32);
    int ar = m16 * 520 + qoff;
    f32x4 ha = {0.f, 0.f, 0.f, 0.f}, hb = {0.f, 0.f, 0.f, 0.f};
#pragma unroll
    for (int kc = 0; kc < 16; ++kc) {
      bf16x8 av = *(const bf16x8*)&h0_s[ar + kc * 32];
      if (kc & 1) hb = MFMA(av, bv[kc], hb, 0, 0, 0);
      else        ha = MFMA(av, bv[kc], ha, 0, 0, 0);
    }
    int n = n0 + m16;
    float sc = g1p[n] * rsqrtf(v1p[n] + BN_EPS);
    float sh = be1p[n] + (b1p[n] - m1p[n]) * sc;
#pragma unroll
    for (int r = 0; r < 4; ++r) {
      float v = fmaxf((ha[r] + hb[r]) * sc + sh, 0.f);
      h1_s[((l >> 4) * 4 + r) * 264 + n] = f2b(v);
    }
  }
  __syncthreads();   // barrier 6

  // layer 2: 256 -> 128, waves 0..7
  if (w < 8) {
    int n0 = w * 16;
    const unsigned short* wp = w2t + (size_t)(n0 + m16) * 256 + qoff;
    bf16x8 bv[8];
#pragma unroll
    for (int kc = 0; kc < 8; ++kc) bv[kc] = *(const bf16x8*)(wp + kc * 32);
    int ar = m16 * 264 + qoff;
    f32x4 ha = {0.f, 0.f, 0.f, 0.f}, hb = {0.f, 0.f, 0.f, 0.f};
#pragma unroll
    for (int kc = 0; kc < 8; ++kc) {
      bf16x8 av = *(const bf16x8*)&h1_s[ar + kc * 32];
      if (kc & 1) hb = MFMA(av, bv[kc], hb, 0, 0, 0);
      else        ha = MFMA(av, bv[kc], ha, 0, 0, 0);
    }
    int n = n0 + m16;
    float sc = g2p[n] * rsqrtf(v2p[n] + BN_EPS);
    float sh = be2p[n] + (b2p[n] - m2p[n]) * sc;
#pragma unroll
    for (int r = 0; r < 4; ++r) {
      float v = fmaxf((ha[r] + hb[r]) * sc + sh, 0.f);
      h2_s[((l >> 4) * 4 + r) * 136 + n] = f2b(v);
    }
  }
  __syncthreads();   // barrier 7

  // output: sigmoid(h2 @ Wout + bout)
  if (t < 128) {
    int bb = t >> 3, seg = t & 7;
    float a = 0.f;
#pragma unroll
    for (int j = 0; j < 16; ++j) {
      int k = seg * 16 + j;
      a += bs2f(h2_s[bb * 136 + k]) * Wout[k];
    }
    a += __shfl_xor(a, 4); a += __shfl_xor(a, 2); a += __shfl_xor(a, 1);
    if (seg == 0) out[b0 + bb] = 1.f / (1.f + expf(-(a + boutp[0])));
  }
}

// ===========================================================================
extern "C" void kernel_launch(void* const* d_in, const int* in_sizes, int n_in,
                              void* d_out, int out_size, void* d_ws, size_t ws_size,
                              hipStream_t stream)
{
  (void)in_sizes; (void)n_in; (void)out_size; (void)ws_size;
  unsigned short* ws = (unsigned short*)d_ws;

  prep<<<292, 256, 0, stream>>>(
      (const float*)d_in[3], (const float*)d_in[5], (const float*)d_in[6],
      (const float*)d_in[12], (const float*)d_in[18], ws);

  pnn_main<<<B / ROWS, 1024, 0, stream>>>(
      (const float*)d_in[0], (const int*)d_in[1], (const float*)d_in[2],
      (const float*)d_in[4], ws,
      (const float*)d_in[7],  (const float*)d_in[8],  (const float*)d_in[9],
      (const float*)d_in[10], (const float*)d_in[11],
      (const float*)d_in[13], (const float*)d_in[14], (const float*)d_in[15],
      (const float*)d_in[16], (const float*)d_in[17],
      (const float*)d_in[19], (const float*)d_in[20], (const float*)d_in[21],
      (const float*)d_in[22], (const float*)d_in[23],
      (const float*)d_in[24], (const float*)d_in[25],
      (float*)d_out);
}